// Round 6
// baseline (1059.591 us; speedup 1.0000x reference)
//
#include <hip/hip_runtime.h>
#include <hip/hip_bf16.h>

// Inputs: fp32, dict order (verified rounds 1-5). Output: fp32 (this round's
// decisive hypothesis). All internal compute fp32.

// ---------------------------------------------------------------------------
// K1: backbone conv (3->256, 3x3, stride16, pad1) fused with 2x2 avgpool.
// Output f NHWC fp32 (8,32,32,256). One block per (b,y,x), thread=cout.
// Validated bit-equal (to bf16 rounding) against naive NCHW rebuild.
// ---------------------------------------------------------------------------
__global__ __launch_bounds__(256) void k_backbone(const float* __restrict__ img,
    const float* __restrict__ w, const float* __restrict__ bias,
    float* __restrict__ f) {
  int blk = blockIdx.x;
  int x = blk & 31, y = (blk >> 5) & 31, b = blk >> 10;
  __shared__ float patch[4 * 27];   // [sub][cin*9+ky*3+kx]
  int t = threadIdx.x;
  if (t < 108) {
    int kx = t % 3, ky = (t / 3) % 3, cin = (t / 9) % 3, sub = t / 27;
    int sy = sub >> 1, sx = sub & 1;
    int iy = (2 * y + sy) * 16 - 1 + ky;   // max 1009 < 1024
    int ix = (2 * x + sx) * 16 - 1 + kx;
    float v = 0.f;
    if (iy >= 0 && ix >= 0)
      v = img[((size_t)(b * 3 + cin) * 1024 + iy) * 1024 + ix];
    patch[t] = v;
  }
  __syncthreads();
  int c = t;
  float wr[27];
#pragma unroll
  for (int k = 0; k < 27; ++k) wr[k] = w[c * 27 + k];
  float acc = 0.f;
#pragma unroll
  for (int sub = 0; sub < 4; ++sub)
#pragma unroll
    for (int k = 0; k < 27; ++k)
      acc += patch[sub * 27 + k] * wr[k];
  f[(size_t)blk * 256 + c] = acc * 0.25f + bias[c];
}

// ---------------------------------------------------------------------------
// K2: RPN conv (only needed at y=0, x=0..3) + delta conv + proposal decode.
// First 100 flat anchors per batch = positions (0,0..3) x 27 anchors (+ 19).
// Grid: 32 blocks (b*4+x), 256 threads.
// ---------------------------------------------------------------------------
__global__ __launch_bounds__(256) void k_proposals(const float* __restrict__ f,
    const float* __restrict__ rpn_w, const float* __restrict__ rpn_b,
    const float* __restrict__ dw, const float* __restrict__ db,
    float* __restrict__ boxes) {
  int x = blockIdx.x & 3, b = blockIdx.x >> 2;
  __shared__ float fp[6 * 256];   // [row(2)][col(3)][cin(256)]
  __shared__ float tbuf[256];
  __shared__ float dvals[135];
  int tid = threadIdx.x;
  for (int i = tid; i < 1536; i += 256) {
    int cin = i & 255, col = (i >> 8) % 3, row = i / 768;
    int xc = x - 1 + col;
    fp[i] = (xc >= 0) ? f[((b * 32 + row) * 32 + xc) * 256 + cin] : 0.f;
  }
  __syncthreads();
  {
    int c = tid;
    float acc = rpn_b[c];
    const float* wbase = rpn_w + (size_t)c * 2304;
    for (int cin = 0; cin < 256; ++cin) {
      const float* wp = wbase + cin * 9;
      // ky=0 hits zero-pad (feature row -1); ky=1 -> row 0; ky=2 -> row 1
      acc += fp[       cin] * wp[3] + fp[ 256 + cin] * wp[4]
           + fp[ 512 + cin] * wp[5] + fp[ 768 + cin] * wp[6]
           + fp[1024 + cin] * wp[7] + fp[1280 + cin] * wp[8];
    }
    tbuf[c] = fmaxf(acc, 0.f);
  }
  __syncthreads();
  if (tid < 135) {
    float a2 = db[tid];
    const float* wp = dw + (size_t)tid * 256;
    for (int cin = 0; cin < 256; ++cin) a2 += tbuf[cin] * wp[cin];
    dvals[tid] = a2;
  }
  __syncthreads();
  if (tid < 27) {
    int i = x * 27 + tid;
    if (i < 100) {
      int a = tid;
      int si = a / 9, ri = (a / 3) % 3, ai = a % 3;
      float scale = 32.f * (float)(1 << si);
      float sr = (ri == 0) ? 0.70710678118654752f : (ri == 1 ? 1.0f : 1.41421356237309505f);
      float aw = scale * sr, ah = scale / sr;
      float aang = 45.f * (float)ai;
      float acx = 32.f * (float)x, acy = 0.f;
      float* bx = boxes + (size_t)(b * 100 + i) * 5;
      bx[0] = dvals[a * 5 + 0] * aw + acx;
      bx[1] = dvals[a * 5 + 1] * ah + acy;
      bx[2] = expf(dvals[a * 5 + 2]) * aw;
      bx[3] = expf(dvals[a * 5 + 3]) * ah;
      bx[4] = aang + dvals[a * 5 + 4];
    }
  }
}

// ---------------------------------------------------------------------------
// K3: rotated ROI align. 800 blocks (one per box), thread = channel.
// f is NHWC so the 4 bilinear taps are lane-coalesced. Output staged in LDS
// in (c*49+bin) order, then written coalesced as fp32.
// ---------------------------------------------------------------------------
__global__ __launch_bounds__(256) void k_roialign(const float* __restrict__ f,
    const float* __restrict__ boxes, float* __restrict__ pooled) {
  int n = blockIdx.x;
  int b = n / 100;
  __shared__ int six[49], siy[49];
  __shared__ float swx[49], swy[49];
  __shared__ float pool_s[12544];
  int tid = threadIdx.x;
  if (tid < 49) {
    float cx = boxes[n * 5 + 0], cy = boxes[n * 5 + 1];
    float w = boxes[n * 5 + 2], h = boxes[n * 5 + 3], ang = boxes[n * 5 + 4];
    float ar = -ang * 0.017453292519943295f;
    float cc = cosf(ar), ss = sinf(ar);
    float t00 = w * (1.f / 32.f) * cc, t01 = -h * (1.f / 32.f) * ss;
    float t02 = cx * (2.f / 32.f) - 1.f;
    float t10 = w * (1.f / 32.f) * ss, t11 = h * (1.f / 32.f) * cc;
    float t12 = cy * (2.f / 32.f) - 1.f;
    int py = tid / 7, px = tid - py * 7;
    float lx = (2.f * px + 1.f) * (1.f / 7.f) - 1.f;
    float ly = (2.f * py + 1.f) * (1.f / 7.f) - 1.f;
    float gx = t00 * lx + t01 * ly + t02;
    float gy = t10 * lx + t11 * ly + t12;
    float ix = ((gx + 1.f) * 32.f - 1.f) * 0.5f;
    float iy = ((gy + 1.f) * 32.f - 1.f) * 0.5f;
    float x0 = floorf(ix), y0 = floorf(iy);
    six[tid] = (int)x0; siy[tid] = (int)y0;
    swx[tid] = ix - x0; swy[tid] = iy - y0;
  }
  __syncthreads();
  const float* fb = f + (size_t)b * 262144;
  int c = tid;
  for (int bin = 0; bin < 49; ++bin) {
    int x0 = six[bin], y0 = siy[bin];
    float wx = swx[bin], wy = swy[bin];
    float acc = 0.f;
    if (x0 >= 0 && x0 < 32 && y0 >= 0 && y0 < 32)
      acc += fb[(y0 * 32 + x0) * 256 + c] * ((1.f - wx) * (1.f - wy));
    if (x0 + 1 >= 0 && x0 + 1 < 32 && y0 >= 0 && y0 < 32)
      acc += fb[(y0 * 32 + x0 + 1) * 256 + c] * (wx * (1.f - wy));
    if (x0 >= 0 && x0 < 32 && y0 + 1 >= 0 && y0 + 1 < 32)
      acc += fb[((y0 + 1) * 32 + x0) * 256 + c] * ((1.f - wx) * wy);
    if (x0 + 1 >= 0 && x0 + 1 < 32 && y0 + 1 >= 0 && y0 + 1 < 32)
      acc += fb[((y0 + 1) * 32 + x0 + 1) * 256 + c] * (wx * wy);
    pool_s[c * 49 + bin] = acc;
  }
  __syncthreads();
  float* po = pooled + (size_t)n * 12544;
  for (int k = tid; k < 12544; k += 256) po[k] = pool_s[k];
}

// ---------------------------------------------------------------------------
// K4/K5: tiled fp32 GEMM, C = relu(A * B^T + bias). A: MxK, B: NxK, C: MxN.
// 64x64 tile, BK=16, 4x4 per thread, fp32 accumulate.
// ---------------------------------------------------------------------------
template <int RELU>
__global__ __launch_bounds__(256) void k_gemm(const float* __restrict__ A,
    const float* __restrict__ B, const float* __restrict__ bias,
    float* __restrict__ C, int M, int N, int K) {
  __shared__ float As[16][64];
  __shared__ float Bs[16][64];
  int t = threadIdx.x;
  int n0 = blockIdx.x * 64, m0 = blockIdx.y * 64;
  int row = t >> 2, q = t & 3;
  int am = m0 + row; if (am > M - 1) am = M - 1;   // clamp (discarded at store)
  const float* Ap = A + (size_t)am * K + q * 4;
  const float* Bp = B + (size_t)(n0 + row) * K + q * 4;
  int ty = t >> 4, tx = t & 15;
  float acc[4][4] = {};
  for (int k0 = 0; k0 < K; k0 += 16) {
    float4 av = *(const float4*)(Ap + k0);
    float4 bv = *(const float4*)(Bp + k0);
    __syncthreads();
    As[q * 4 + 0][row] = av.x;
    As[q * 4 + 1][row] = av.y;
    As[q * 4 + 2][row] = av.z;
    As[q * 4 + 3][row] = av.w;
    Bs[q * 4 + 0][row] = bv.x;
    Bs[q * 4 + 1][row] = bv.y;
    Bs[q * 4 + 2][row] = bv.z;
    Bs[q * 4 + 3][row] = bv.w;
    __syncthreads();
#pragma unroll
    for (int kk = 0; kk < 16; ++kk) {
      const float4 a4 = *(const float4*)&As[kk][ty * 4];
      const float4 b4 = *(const float4*)&Bs[kk][tx * 4];
      float a[4] = {a4.x, a4.y, a4.z, a4.w};
      float bb[4] = {b4.x, b4.y, b4.z, b4.w};
#pragma unroll
      for (int i = 0; i < 4; ++i)
#pragma unroll
        for (int j = 0; j < 4; ++j)
          acc[i][j] += a[i] * bb[j];
    }
  }
#pragma unroll
  for (int i = 0; i < 4; ++i) {
    int m = m0 + ty * 4 + i;
    if (m >= M) continue;
#pragma unroll
    for (int j = 0; j < 4; ++j) {
      int n = n0 + tx * 4 + j;
      float v = acc[i][j] + bias[n];
      if (RELU) v = fmaxf(v, 0.f);
      C[(size_t)m * N + n] = v;
    }
  }
}

// ---------------------------------------------------------------------------
// K6: heads. One block per row, one wave per output (5 cls + 5 bbox).
// Output fp32, concat [class_logits(800x5); obb_preds(800x5)].
// ---------------------------------------------------------------------------
__global__ __launch_bounds__(640) void k_heads(const float* __restrict__ x2,
    const float* __restrict__ cls_w, const float* __restrict__ cls_b,
    const float* __restrict__ bbox_w, const float* __restrict__ bbox_b,
    float* __restrict__ out) {
  int n = blockIdx.x;
  int wave = threadIdx.x >> 6;   // 0..9
  int lane = threadIdx.x & 63;
  const float* w = (wave < 5) ? (cls_w + (size_t)wave * 1024)
                              : (bbox_w + (size_t)(wave - 5) * 1024);
  const float* xr = x2 + (size_t)n * 1024;
  float s = 0.f;
  for (int k = lane; k < 1024; k += 64) s += xr[k] * w[k];
  for (int off = 32; off; off >>= 1) s += __shfl_down(s, off, 64);
  if (lane == 0) {
    int o = (wave < 5) ? wave : wave - 5;
    float bias = (wave < 5) ? cls_b[o] : bbox_b[o];
    int base = (wave < 5) ? 0 : 4000;
    out[base + n * 5 + o] = s + bias;
  }
}

// ---------------------------------------------------------------------------
extern "C" void kernel_launch(void* const* d_in, const int* in_sizes, int n_in,
                              void* d_out, int out_size, void* d_ws, size_t ws_size,
                              hipStream_t stream) {
  const float* images     = (const float*)d_in[0];
  const float* backbone_w = (const float*)d_in[1];
  const float* backbone_b = (const float*)d_in[2];
  const float* rpn_w      = (const float*)d_in[3];
  const float* rpn_b      = (const float*)d_in[4];
  // d_in[5]/d_in[6] (obj_w/obj_b): conv output unused by the reference.
  const float* delta_w    = (const float*)d_in[7];
  const float* delta_b    = (const float*)d_in[8];
  const float* fc1_w      = (const float*)d_in[9];
  const float* fc1_b      = (const float*)d_in[10];
  const float* fc2_w      = (const float*)d_in[11];
  const float* fc2_b      = (const float*)d_in[12];
  const float* cls_w      = (const float*)d_in[13];
  const float* cls_b      = (const float*)d_in[14];
  const float* bbox_w     = (const float*)d_in[15];
  const float* bbox_b     = (const float*)d_in[16];

  char* ws = (char*)d_ws;
  float* f      = (float*)ws;                  //  8,388,608 B : f NHWC fp32
  float* boxes  = (float*)(ws + 8388608);      //     16,000 B : 800x5 fp32
  float* pooled = (float*)(ws + 8404992);      // 40,140,800 B : 800x12544 fp32
  float* x1     = (float*)(ws + 48545792);     //  3,276,800 B : 800x1024 fp32
  float* x2     = (float*)(ws + 51822592);     //  3,276,800 B -> 55.1 MB total

  k_backbone<<<8192, 256, 0, stream>>>(images, backbone_w, backbone_b, f);
  k_proposals<<<32, 256, 0, stream>>>(f, rpn_w, rpn_b, delta_w, delta_b, boxes);
  k_roialign<<<800, 256, 0, stream>>>(f, boxes, pooled);
  k_gemm<1><<<dim3(16, 13), 256, 0, stream>>>(pooled, fc1_w, fc1_b, x1, 800, 1024, 12544);
  k_gemm<1><<<dim3(16, 13), 256, 0, stream>>>(x1, fc2_w, fc2_b, x2, 800, 1024, 1024);
  k_heads<<<800, 640, 0, stream>>>(x2, cls_w, cls_b, bbox_w, bbox_b, (float*)d_out);
}

// Round 7
// 591.651 us; speedup vs baseline: 1.7909x; 1.7909x over previous
//
#include <hip/hip_runtime.h>
#include <hip/hip_bf16.h>

using bf16 = __hip_bfloat16;

typedef __attribute__((ext_vector_type(8))) short bf16x8;
typedef __attribute__((ext_vector_type(4))) float f32x4;

// async global->LDS, 16 B per lane, wave-uniform LDS base (+lane*16 by HW).
__device__ __forceinline__ void async16(const void* g, void* l) {
  __builtin_amdgcn_global_load_lds(
      (const __attribute__((address_space(1))) unsigned int*)g,
      (__attribute__((address_space(3))) unsigned int*)l, 16, 0, 0);
}

__device__ __forceinline__ void store_o(float* C, size_t i, float v) { C[i] = v; }
__device__ __forceinline__ void store_o(bf16* C, size_t i, float v) {
  C[i] = __float2bfloat16(v);
}

// ---------------------------------------------------------------------------
// K1: backbone conv (3->256, 3x3, stride16, pad1) fused with 2x2 avgpool.
// Output f NHWC fp32 (8,32,32,256). One block per (b,y,x), thread=cout.
// ---------------------------------------------------------------------------
__global__ __launch_bounds__(256) void k_backbone(const float* __restrict__ img,
    const float* __restrict__ w, const float* __restrict__ bias,
    float* __restrict__ f) {
  int blk = blockIdx.x;
  int x = blk & 31, y = (blk >> 5) & 31, b = blk >> 10;
  __shared__ float patch[4 * 27];   // [sub][cin*9+ky*3+kx]
  int t = threadIdx.x;
  if (t < 108) {
    int kx = t % 3, ky = (t / 3) % 3, cin = (t / 9) % 3, sub = t / 27;
    int sy = sub >> 1, sx = sub & 1;
    int iy = (2 * y + sy) * 16 - 1 + ky;   // max 1009 < 1024
    int ix = (2 * x + sx) * 16 - 1 + kx;
    float v = 0.f;
    if (iy >= 0 && ix >= 0)
      v = img[((size_t)(b * 3 + cin) * 1024 + iy) * 1024 + ix];
    patch[t] = v;
  }
  __syncthreads();
  int c = t;
  float wr[27];
#pragma unroll
  for (int k = 0; k < 27; ++k) wr[k] = w[c * 27 + k];
  float acc = 0.f;
#pragma unroll
  for (int sub = 0; sub < 4; ++sub)
#pragma unroll
    for (int k = 0; k < 27; ++k)
      acc += patch[sub * 27 + k] * wr[k];
  f[(size_t)blk * 256 + c] = acc * 0.25f + bias[c];
}

// ---------------------------------------------------------------------------
// K2: RPN conv (y=0, x=0..3 only) + delta conv + proposal decode.
// ---------------------------------------------------------------------------
__global__ __launch_bounds__(256) void k_proposals(const float* __restrict__ f,
    const float* __restrict__ rpn_w, const float* __restrict__ rpn_b,
    const float* __restrict__ dw, const float* __restrict__ db,
    float* __restrict__ boxes) {
  int x = blockIdx.x & 3, b = blockIdx.x >> 2;
  __shared__ float fp[6 * 256];   // [row(2)][col(3)][cin(256)]
  __shared__ float tbuf[256];
  __shared__ float dvals[135];
  int tid = threadIdx.x;
  for (int i = tid; i < 1536; i += 256) {
    int cin = i & 255, col = (i >> 8) % 3, row = i / 768;
    int xc = x - 1 + col;
    fp[i] = (xc >= 0) ? f[((b * 32 + row) * 32 + xc) * 256 + cin] : 0.f;
  }
  __syncthreads();
  {
    int c = tid;
    float acc = rpn_b[c];
    const float* wbase = rpn_w + (size_t)c * 2304;
    for (int cin = 0; cin < 256; ++cin) {
      const float* wp = wbase + cin * 9;
      acc += fp[       cin] * wp[3] + fp[ 256 + cin] * wp[4]
           + fp[ 512 + cin] * wp[5] + fp[ 768 + cin] * wp[6]
           + fp[1024 + cin] * wp[7] + fp[1280 + cin] * wp[8];
    }
    tbuf[c] = fmaxf(acc, 0.f);
  }
  __syncthreads();
  if (tid < 135) {
    float a2 = db[tid];
    const float* wp = dw + (size_t)tid * 256;
    for (int cin = 0; cin < 256; ++cin) a2 += tbuf[cin] * wp[cin];
    dvals[tid] = a2;
  }
  __syncthreads();
  if (tid < 27) {
    int i = x * 27 + tid;
    if (i < 100) {
      int a = tid;
      int si = a / 9, ri = (a / 3) % 3, ai = a % 3;
      float scale = 32.f * (float)(1 << si);
      float sr = (ri == 0) ? 0.70710678118654752f : (ri == 1 ? 1.0f : 1.41421356237309505f);
      float aw = scale * sr, ah = scale / sr;
      float aang = 45.f * (float)ai;
      float acx = 32.f * (float)x, acy = 0.f;
      float* bx = boxes + (size_t)(b * 100 + i) * 5;
      bx[0] = dvals[a * 5 + 0] * aw + acx;
      bx[1] = dvals[a * 5 + 1] * ah + acy;
      bx[2] = expf(dvals[a * 5 + 2]) * aw;
      bx[3] = expf(dvals[a * 5 + 3]) * ah;
      bx[4] = aang + dvals[a * 5 + 4];
    }
  }
}

// ---------------------------------------------------------------------------
// K3: rotated ROI align. 800 blocks, thread=channel; writes pooled as bf16
// in (n, c*49+bin) order — the A operand of the FC1 MFMA GEMM.
// ---------------------------------------------------------------------------
__global__ __launch_bounds__(256) void k_roialign(const float* __restrict__ f,
    const float* __restrict__ boxes, bf16* __restrict__ pooled) {
  int n = blockIdx.x;
  int b = n / 100;
  __shared__ int six[49], siy[49];
  __shared__ float swx[49], swy[49];
  __shared__ float pool_s[12544];
  int tid = threadIdx.x;
  if (tid < 49) {
    float cx = boxes[n * 5 + 0], cy = boxes[n * 5 + 1];
    float w = boxes[n * 5 + 2], h = boxes[n * 5 + 3], ang = boxes[n * 5 + 4];
    float ar = -ang * 0.017453292519943295f;
    float cc = cosf(ar), ss = sinf(ar);
    float t00 = w * (1.f / 32.f) * cc, t01 = -h * (1.f / 32.f) * ss;
    float t02 = cx * (2.f / 32.f) - 1.f;
    float t10 = w * (1.f / 32.f) * ss, t11 = h * (1.f / 32.f) * cc;
    float t12 = cy * (2.f / 32.f) - 1.f;
    int py = tid / 7, px = tid - py * 7;
    float lx = (2.f * px + 1.f) * (1.f / 7.f) - 1.f;
    float ly = (2.f * py + 1.f) * (1.f / 7.f) - 1.f;
    float gx = t00 * lx + t01 * ly + t02;
    float gy = t10 * lx + t11 * ly + t12;
    float ix = ((gx + 1.f) * 32.f - 1.f) * 0.5f;
    float iy = ((gy + 1.f) * 32.f - 1.f) * 0.5f;
    float x0 = floorf(ix), y0 = floorf(iy);
    six[tid] = (int)x0; siy[tid] = (int)y0;
    swx[tid] = ix - x0; swy[tid] = iy - y0;
  }
  __syncthreads();
  const float* fb = f + (size_t)b * 262144;
  int c = tid;
  for (int bin = 0; bin < 49; ++bin) {
    int x0 = six[bin], y0 = siy[bin];
    float wx = swx[bin], wy = swy[bin];
    float acc = 0.f;
    if (x0 >= 0 && x0 < 32 && y0 >= 0 && y0 < 32)
      acc += fb[(y0 * 32 + x0) * 256 + c] * ((1.f - wx) * (1.f - wy));
    if (x0 + 1 >= 0 && x0 + 1 < 32 && y0 >= 0 && y0 < 32)
      acc += fb[(y0 * 32 + x0 + 1) * 256 + c] * (wx * (1.f - wy));
    if (x0 >= 0 && x0 < 32 && y0 + 1 >= 0 && y0 + 1 < 32)
      acc += fb[((y0 + 1) * 32 + x0) * 256 + c] * ((1.f - wx) * wy);
    if (x0 + 1 >= 0 && x0 + 1 < 32 && y0 + 1 >= 0 && y0 + 1 < 32)
      acc += fb[((y0 + 1) * 32 + x0 + 1) * 256 + c] * (wx * wy);
    pool_s[c * 49 + bin] = acc;
  }
  __syncthreads();
  bf16* po = pooled + (size_t)n * 12544;
  for (int k = tid; k < 12544; k += 256) po[k] = __float2bfloat16(pool_s[k]);
}

// ---------------------------------------------------------------------------
// K4/K5: MFMA GEMM, C = relu(A * B^T + bias).
// A: MxK bf16 (async-staged to LDS), B: NxK fp32 (staged with inline bf16
// cvt), C: MxN OutT, fp32 accumulate. 64x64 tile, BK=64, 4 waves.
// Fragment layouts per m89/m91/m97-verified mappings:
//   a-frag: A[m=lane&15][k=quad*8+j]; b-frag: Bt[n=lane&15][k=quad*8+j];
//   D[m=quad*4+reg][n=lane&15].
// ---------------------------------------------------------------------------
template <typename OutT>
__global__ __launch_bounds__(256) void k_gemm_mfma(
    const unsigned short* __restrict__ A, const float* __restrict__ B,
    const float* __restrict__ bias, OutT* __restrict__ C,
    int M, int N, int K) {
  __shared__ unsigned short As[64 * 64];   // [m][k] row-major, 8 KB
  __shared__ unsigned short Bs[64 * 64];   // [n][k] row-major, 8 KB
  int t = threadIdx.x;
  int wv = t >> 6, ln = t & 63;
  int quad = ln >> 4, l15 = ln & 15;
  int n0 = blockIdx.x * 64, m0 = blockIdx.y * 64;

  // A staging: call i covers tile rows i*32 + (t>>3), 16B seg (t&7).
  int ar = t >> 3, aseg = t & 7;
  int r0 = m0 + ar;      if (r0 > M - 1) r0 = M - 1;
  int r1 = m0 + ar + 32; if (r1 > M - 1) r1 = M - 1;
  const unsigned short* Ap0 = A + (size_t)r0 * K + aseg * 8;
  const unsigned short* Ap1 = A + (size_t)r1 * K + aseg * 8;
  unsigned short* ldsA0 = &As[wv * 512];          // +wave*1024 B
  unsigned short* ldsA1 = &As[2048 + wv * 512];
  // B staging: thread covers row t>>2, 16 floats at (t&3)*16.
  int brow = t >> 2, bq = t & 3;
  const float* Bp = B + (size_t)(n0 + brow) * K + bq * 16;
  unsigned short* bdst = &Bs[brow * 64 + bq * 16];

  f32x4 acc[4];
#pragma unroll
  for (int j = 0; j < 4; ++j) acc[j] = (f32x4){0.f, 0.f, 0.f, 0.f};

  int a_off = (wv * 16 + l15) * 64 + quad * 8;
  int b_off = l15 * 64 + quad * 8;

  for (int k0 = 0; k0 < K; k0 += 64) {
    float4 bv0 = *(const float4*)(Bp + k0);
    float4 bv1 = *(const float4*)(Bp + k0 + 4);
    float4 bv2 = *(const float4*)(Bp + k0 + 8);
    float4 bv3 = *(const float4*)(Bp + k0 + 12);
    __syncthreads();   // previous iteration's compute done
    async16(Ap0 + k0, ldsA0);
    async16(Ap1 + k0, ldsA1);
    unsigned short bb[16];
    bb[0]  = __bfloat16_as_ushort(__float2bfloat16(bv0.x));
    bb[1]  = __bfloat16_as_ushort(__float2bfloat16(bv0.y));
    bb[2]  = __bfloat16_as_ushort(__float2bfloat16(bv0.z));
    bb[3]  = __bfloat16_as_ushort(__float2bfloat16(bv0.w));
    bb[4]  = __bfloat16_as_ushort(__float2bfloat16(bv1.x));
    bb[5]  = __bfloat16_as_ushort(__float2bfloat16(bv1.y));
    bb[6]  = __bfloat16_as_ushort(__float2bfloat16(bv1.z));
    bb[7]  = __bfloat16_as_ushort(__float2bfloat16(bv1.w));
    bb[8]  = __bfloat16_as_ushort(__float2bfloat16(bv2.x));
    bb[9]  = __bfloat16_as_ushort(__float2bfloat16(bv2.y));
    bb[10] = __bfloat16_as_ushort(__float2bfloat16(bv2.z));
    bb[11] = __bfloat16_as_ushort(__float2bfloat16(bv2.w));
    bb[12] = __bfloat16_as_ushort(__float2bfloat16(bv3.x));
    bb[13] = __bfloat16_as_ushort(__float2bfloat16(bv3.y));
    bb[14] = __bfloat16_as_ushort(__float2bfloat16(bv3.z));
    bb[15] = __bfloat16_as_ushort(__float2bfloat16(bv3.w));
#pragma unroll
    for (int u = 0; u < 2; ++u)
      *(bf16x8*)(bdst + u * 8) = *(const bf16x8*)(bb + u * 8);
    __syncthreads();   // drains vmcnt (async A) + lgkm (B writes)
#pragma unroll
    for (int ks = 0; ks < 2; ++ks) {
      bf16x8 a = *(const bf16x8*)&As[a_off + ks * 32];
#pragma unroll
      for (int j = 0; j < 4; ++j) {
        bf16x8 b = *(const bf16x8*)&Bs[b_off + j * 1024 + ks * 32];
        acc[j] = __builtin_amdgcn_mfma_f32_16x16x32_bf16(a, b, acc[j], 0, 0, 0);
      }
    }
  }
#pragma unroll
  for (int j = 0; j < 4; ++j) {
    int n = n0 + j * 16 + l15;
    float bz = bias[n];
#pragma unroll
    for (int r = 0; r < 4; ++r) {
      int m = m0 + wv * 16 + quad * 4 + r;
      if (m < M) {
        float v = fmaxf(acc[j][r] + bz, 0.f);
        store_o(C, (size_t)m * N + n, v);
      }
    }
  }
}

// ---------------------------------------------------------------------------
// K6: heads. One block per row, one wave per output (5 cls + 5 bbox).
// Output fp32, concat [class_logits(800x5); obb_preds(800x5)].
// ---------------------------------------------------------------------------
__global__ __launch_bounds__(640) void k_heads(const float* __restrict__ x2,
    const float* __restrict__ cls_w, const float* __restrict__ cls_b,
    const float* __restrict__ bbox_w, const float* __restrict__ bbox_b,
    float* __restrict__ out) {
  int n = blockIdx.x;
  int wave = threadIdx.x >> 6;   // 0..9
  int lane = threadIdx.x & 63;
  const float* w = (wave < 5) ? (cls_w + (size_t)wave * 1024)
                              : (bbox_w + (size_t)(wave - 5) * 1024);
  const float* xr = x2 + (size_t)n * 1024;
  float s = 0.f;
  for (int k = lane; k < 1024; k += 64) s += xr[k] * w[k];
  for (int off = 32; off; off >>= 1) s += __shfl_down(s, off, 64);
  if (lane == 0) {
    int o = (wave < 5) ? wave : wave - 5;
    float bias = (wave < 5) ? cls_b[o] : bbox_b[o];
    int base = (wave < 5) ? 0 : 4000;
    out[base + n * 5 + o] = s + bias;
  }
}

// ---------------------------------------------------------------------------
extern "C" void kernel_launch(void* const* d_in, const int* in_sizes, int n_in,
                              void* d_out, int out_size, void* d_ws, size_t ws_size,
                              hipStream_t stream) {
  const float* images     = (const float*)d_in[0];
  const float* backbone_w = (const float*)d_in[1];
  const float* backbone_b = (const float*)d_in[2];
  const float* rpn_w      = (const float*)d_in[3];
  const float* rpn_b      = (const float*)d_in[4];
  // d_in[5]/d_in[6] (obj_w/obj_b): conv output unused by the reference.
  const float* delta_w    = (const float*)d_in[7];
  const float* delta_b    = (const float*)d_in[8];
  const float* fc1_w      = (const float*)d_in[9];
  const float* fc1_b      = (const float*)d_in[10];
  const float* fc2_w      = (const float*)d_in[11];
  const float* fc2_b      = (const float*)d_in[12];
  const float* cls_w      = (const float*)d_in[13];
  const float* cls_b      = (const float*)d_in[14];
  const float* bbox_w     = (const float*)d_in[15];
  const float* bbox_b     = (const float*)d_in[16];

  char* ws = (char*)d_ws;
  float* f      = (float*)ws;                  //  8,388,608 B : f NHWC fp32
  float* boxes  = (float*)(ws + 8388608);      //     16,000 B (pad 16,384)
  bf16*  pooled = (bf16*) (ws + 8404992);      // 20,070,400 B : 800x12544 bf16
  bf16*  x1     = (bf16*) (ws + 28475392);     //  1,638,400 B : 800x1024 bf16
  float* x2     = (float*)(ws + 30113792);     //  3,276,800 B -> 33.4 MB total

  k_backbone<<<8192, 256, 0, stream>>>(images, backbone_w, backbone_b, f);
  k_proposals<<<32, 256, 0, stream>>>(f, rpn_w, rpn_b, delta_w, delta_b, boxes);
  k_roialign<<<800, 256, 0, stream>>>(f, boxes, pooled);
  k_gemm_mfma<bf16><<<dim3(16, 13), 256, 0, stream>>>(
      (const unsigned short*)pooled, fc1_w, fc1_b, x1, 800, 1024, 12544);
  k_gemm_mfma<float><<<dim3(16, 13), 256, 0, stream>>>(
      (const unsigned short*)x1, fc2_w, fc2_b, x2, 800, 1024, 1024);
  k_heads<<<800, 640, 0, stream>>>(x2, cls_w, cls_b, bbox_w, bbox_b, (float*)d_out);
}

// Round 8
// 427.354 us; speedup vs baseline: 2.4794x; 1.3845x over previous
//
#include <hip/hip_runtime.h>
#include <hip/hip_bf16.h>

using bf16 = __hip_bfloat16;

typedef __attribute__((ext_vector_type(8))) short bf16x8;
typedef __attribute__((ext_vector_type(4))) float f32x4;

// async global->LDS, 16 B per lane, wave-uniform LDS base (+lane*16 by HW).
__device__ __forceinline__ void async16(const void* g, void* l) {
  __builtin_amdgcn_global_load_lds(
      (const __attribute__((address_space(1))) unsigned int*)g,
      (__attribute__((address_space(3))) unsigned int*)l, 16, 0, 0);
}

__device__ __forceinline__ void store_o(float* C, size_t i, float v) { C[i] = v; }
__device__ __forceinline__ void store_o(bf16* C, size_t i, float v) {
  C[i] = __float2bfloat16(v);
}

// ---------------------------------------------------------------------------
// K1: backbone conv (3->256, 3x3, stride16, pad1) fused with 2x2 avgpool.
// Output f NHWC fp32 (8,32,32,256). One block per (b,y,x), thread=cout.
// ---------------------------------------------------------------------------
__global__ __launch_bounds__(256) void k_backbone(const float* __restrict__ img,
    const float* __restrict__ w, const float* __restrict__ bias,
    float* __restrict__ f) {
  int blk = blockIdx.x;
  int x = blk & 31, y = (blk >> 5) & 31, b = blk >> 10;
  __shared__ float patch[4 * 27];   // [sub][cin*9+ky*3+kx]
  int t = threadIdx.x;
  if (t < 108) {
    int kx = t % 3, ky = (t / 3) % 3, cin = (t / 9) % 3, sub = t / 27;
    int sy = sub >> 1, sx = sub & 1;
    int iy = (2 * y + sy) * 16 - 1 + ky;   // max 1009 < 1024
    int ix = (2 * x + sx) * 16 - 1 + kx;
    float v = 0.f;
    if (iy >= 0 && ix >= 0)
      v = img[((size_t)(b * 3 + cin) * 1024 + iy) * 1024 + ix];
    patch[t] = v;
  }
  __syncthreads();
  int c = t;
  float wr[27];
#pragma unroll
  for (int k = 0; k < 27; ++k) wr[k] = w[c * 27 + k];
  float acc = 0.f;
#pragma unroll
  for (int sub = 0; sub < 4; ++sub)
#pragma unroll
    for (int k = 0; k < 27; ++k)
      acc += patch[sub * 27 + k] * wr[k];
  f[(size_t)blk * 256 + c] = acc * 0.25f + bias[c];
}

// ---------------------------------------------------------------------------
// K2: RPN conv (y=0, x=0..3 only) + delta conv + proposal decode.
// ---------------------------------------------------------------------------
__global__ __launch_bounds__(256) void k_proposals(const float* __restrict__ f,
    const float* __restrict__ rpn_w, const float* __restrict__ rpn_b,
    const float* __restrict__ dw, const float* __restrict__ db,
    float* __restrict__ boxes) {
  int x = blockIdx.x & 3, b = blockIdx.x >> 2;
  __shared__ float fp[6 * 256];   // [row(2)][col(3)][cin(256)]
  __shared__ float tbuf[256];
  __shared__ float dvals[135];
  int tid = threadIdx.x;
  for (int i = tid; i < 1536; i += 256) {
    int cin = i & 255, col = (i >> 8) % 3, row = i / 768;
    int xc = x - 1 + col;
    fp[i] = (xc >= 0) ? f[((b * 32 + row) * 32 + xc) * 256 + cin] : 0.f;
  }
  __syncthreads();
  {
    int c = tid;
    float acc = rpn_b[c];
    const float* wbase = rpn_w + (size_t)c * 2304;
    for (int cin = 0; cin < 256; ++cin) {
      const float* wp = wbase + cin * 9;
      acc += fp[       cin] * wp[3] + fp[ 256 + cin] * wp[4]
           + fp[ 512 + cin] * wp[5] + fp[ 768 + cin] * wp[6]
           + fp[1024 + cin] * wp[7] + fp[1280 + cin] * wp[8];
    }
    tbuf[c] = fmaxf(acc, 0.f);
  }
  __syncthreads();
  if (tid < 135) {
    float a2 = db[tid];
    const float* wp = dw + (size_t)tid * 256;
    for (int cin = 0; cin < 256; ++cin) a2 += tbuf[cin] * wp[cin];
    dvals[tid] = a2;
  }
  __syncthreads();
  if (tid < 27) {
    int i = x * 27 + tid;
    if (i < 100) {
      int a = tid;
      int si = a / 9, ri = (a / 3) % 3, ai = a % 3;
      float scale = 32.f * (float)(1 << si);
      float sr = (ri == 0) ? 0.70710678118654752f : (ri == 1 ? 1.0f : 1.41421356237309505f);
      float aw = scale * sr, ah = scale / sr;
      float aang = 45.f * (float)ai;
      float acx = 32.f * (float)x, acy = 0.f;
      float* bx = boxes + (size_t)(b * 100 + i) * 5;
      bx[0] = dvals[a * 5 + 0] * aw + acx;
      bx[1] = dvals[a * 5 + 1] * ah + acy;
      bx[2] = expf(dvals[a * 5 + 2]) * aw;
      bx[3] = expf(dvals[a * 5 + 3]) * ah;
      bx[4] = aang + dvals[a * 5 + 4];
    }
  }
}

// ---------------------------------------------------------------------------
// K3: rotated ROI align. 800 blocks, thread=channel; writes pooled as bf16
// in (n, c*49+bin) order — the A operand of the FC1 MFMA GEMM.
// ---------------------------------------------------------------------------
__global__ __launch_bounds__(256) void k_roialign(const float* __restrict__ f,
    const float* __restrict__ boxes, bf16* __restrict__ pooled) {
  int n = blockIdx.x;
  int b = n / 100;
  __shared__ int six[49], siy[49];
  __shared__ float swx[49], swy[49];
  __shared__ float pool_s[12544];
  int tid = threadIdx.x;
  if (tid < 49) {
    float cx = boxes[n * 5 + 0], cy = boxes[n * 5 + 1];
    float w = boxes[n * 5 + 2], h = boxes[n * 5 + 3], ang = boxes[n * 5 + 4];
    float ar = -ang * 0.017453292519943295f;
    float cc = cosf(ar), ss = sinf(ar);
    float t00 = w * (1.f / 32.f) * cc, t01 = -h * (1.f / 32.f) * ss;
    float t02 = cx * (2.f / 32.f) - 1.f;
    float t10 = w * (1.f / 32.f) * ss, t11 = h * (1.f / 32.f) * cc;
    float t12 = cy * (2.f / 32.f) - 1.f;
    int py = tid / 7, px = tid - py * 7;
    float lx = (2.f * px + 1.f) * (1.f / 7.f) - 1.f;
    float ly = (2.f * py + 1.f) * (1.f / 7.f) - 1.f;
    float gx = t00 * lx + t01 * ly + t02;
    float gy = t10 * lx + t11 * ly + t12;
    float ix = ((gx + 1.f) * 32.f - 1.f) * 0.5f;
    float iy = ((gy + 1.f) * 32.f - 1.f) * 0.5f;
    float x0 = floorf(ix), y0 = floorf(iy);
    six[tid] = (int)x0; siy[tid] = (int)y0;
    swx[tid] = ix - x0; swy[tid] = iy - y0;
  }
  __syncthreads();
  const float* fb = f + (size_t)b * 262144;
  int c = tid;
  for (int bin = 0; bin < 49; ++bin) {
    int x0 = six[bin], y0 = siy[bin];
    float wx = swx[bin], wy = swy[bin];
    float acc = 0.f;
    if (x0 >= 0 && x0 < 32 && y0 >= 0 && y0 < 32)
      acc += fb[(y0 * 32 + x0) * 256 + c] * ((1.f - wx) * (1.f - wy));
    if (x0 + 1 >= 0 && x0 + 1 < 32 && y0 >= 0 && y0 < 32)
      acc += fb[(y0 * 32 + x0 + 1) * 256 + c] * (wx * (1.f - wy));
    if (x0 >= 0 && x0 < 32 && y0 + 1 >= 0 && y0 + 1 < 32)
      acc += fb[((y0 + 1) * 32 + x0) * 256 + c] * ((1.f - wx) * wy);
    if (x0 + 1 >= 0 && x0 + 1 < 32 && y0 + 1 >= 0 && y0 + 1 < 32)
      acc += fb[((y0 + 1) * 32 + x0 + 1) * 256 + c] * (wx * wy);
    pool_s[c * 49 + bin] = acc;
  }
  __syncthreads();
  bf16* po = pooled + (size_t)n * 12544;
  for (int k = tid; k < 12544; k += 256) po[k] = __float2bfloat16(pool_s[k]);
}

// ---------------------------------------------------------------------------
// K4: split-K MFMA GEMM partial: P[z] = A[:, kbeg:kend] * B[:, kbeg:kend]^T.
// A: MxK bf16 (async LDS, XOR-seg swizzle vs 128B-row bank aliasing),
// B: NxK fp32 (inline cvt, rows padded to 72 shorts), fp32 partials.
// 64x64 tile, BK=64, 4 waves. grid (N/64, ceil(M/64), KS).
// ---------------------------------------------------------------------------
__global__ __launch_bounds__(256) void k_gemm_sk(
    const unsigned short* __restrict__ A, const float* __restrict__ B,
    float* __restrict__ P, int M, int N, int K, int KC) {
  __shared__ unsigned short As[64 * 64];   // 8 KB, XOR-swizzled segs
  __shared__ unsigned short Bs[64 * 72];   // 9 KB, padded rows
  int t = threadIdx.x;
  int wv = t >> 6, ln = t & 63;
  int quad = ln >> 4, l15 = ln & 15;
  int n0 = blockIdx.x * 64, m0 = blockIdx.y * 64;
  int kbeg = blockIdx.z * KC;
  int kend = kbeg + KC; if (kend > K) kend = K;

  // A staging: lane covers (row arow(+32), global seg sg); LDS slot fixed at
  // wave_base + lane*16 == row*128 + (sg ^ (row&7))*16  (XOR swizzle).
  int arow = wv * 8 + (ln >> 3);
  int sg = (ln & 7) ^ (arow & 7);
  int r0 = m0 + arow;      if (r0 > M - 1) r0 = M - 1;
  int r1 = m0 + arow + 32; if (r1 > M - 1) r1 = M - 1;
  const unsigned short* Ap0 = A + (size_t)r0 * K + sg * 8;
  const unsigned short* Ap1 = A + (size_t)r1 * K + sg * 8;
  unsigned short* ldsA0 = &As[wv * 512];
  unsigned short* ldsA1 = &As[2048 + wv * 512];

  // B staging: thread covers row t>>2, 16 floats at (t&3)*16.
  int brow = t >> 2, bq = t & 3;
  const float* Bp = B + (size_t)(n0 + brow) * K + bq * 16;
  unsigned short* bdst = &Bs[brow * 72 + bq * 16];

  f32x4 acc[4];
#pragma unroll
  for (int j = 0; j < 4; ++j) acc[j] = (f32x4){0.f, 0.f, 0.f, 0.f};

  int mrow = wv * 16 + l15;   // this lane's A fragment row

  for (int k0 = kbeg; k0 < kend; k0 += 64) {
    float4 bv0 = *(const float4*)(Bp + k0);
    float4 bv1 = *(const float4*)(Bp + k0 + 4);
    float4 bv2 = *(const float4*)(Bp + k0 + 8);
    float4 bv3 = *(const float4*)(Bp + k0 + 12);
    __syncthreads();   // previous iteration's compute done
    async16(Ap0 + k0, ldsA0);
    async16(Ap1 + k0, ldsA1);
    unsigned short bb[16];
    bb[0]  = __bfloat16_as_ushort(__float2bfloat16(bv0.x));
    bb[1]  = __bfloat16_as_ushort(__float2bfloat16(bv0.y));
    bb[2]  = __bfloat16_as_ushort(__float2bfloat16(bv0.z));
    bb[3]  = __bfloat16_as_ushort(__float2bfloat16(bv0.w));
    bb[4]  = __bfloat16_as_ushort(__float2bfloat16(bv1.x));
    bb[5]  = __bfloat16_as_ushort(__float2bfloat16(bv1.y));
    bb[6]  = __bfloat16_as_ushort(__float2bfloat16(bv1.z));
    bb[7]  = __bfloat16_as_ushort(__float2bfloat16(bv1.w));
    bb[8]  = __bfloat16_as_ushort(__float2bfloat16(bv2.x));
    bb[9]  = __bfloat16_as_ushort(__float2bfloat16(bv2.y));
    bb[10] = __bfloat16_as_ushort(__float2bfloat16(bv2.z));
    bb[11] = __bfloat16_as_ushort(__float2bfloat16(bv2.w));
    bb[12] = __bfloat16_as_ushort(__float2bfloat16(bv3.x));
    bb[13] = __bfloat16_as_ushort(__float2bfloat16(bv3.y));
    bb[14] = __bfloat16_as_ushort(__float2bfloat16(bv3.z));
    bb[15] = __bfloat16_as_ushort(__float2bfloat16(bv3.w));
#pragma unroll
    for (int u = 0; u < 2; ++u)
      *(bf16x8*)(bdst + u * 8) = *(const bf16x8*)(bb + u * 8);
    __syncthreads();   // drains vmcnt (async A) + lgkm (B writes)
#pragma unroll
    for (int ks = 0; ks < 2; ++ks) {
      bf16x8 a = *(const bf16x8*)&As[mrow * 64 + (((ks * 4 + quad) ^ (mrow & 7)) * 8)];
#pragma unroll
      for (int j = 0; j < 4; ++j) {
        bf16x8 b = *(const bf16x8*)&Bs[(j * 16 + l15) * 72 + ks * 32 + quad * 8];
        acc[j] = __builtin_amdgcn_mfma_f32_16x16x32_bf16(a, b, acc[j], 0, 0, 0);
      }
    }
  }
  // store fp32 partials; D layout m = quad*4+r, n = l15 (within 16x16).
  float* Pz = P + (size_t)blockIdx.z * M * N;
#pragma unroll
  for (int j = 0; j < 4; ++j) {
    int n = n0 + j * 16 + l15;
#pragma unroll
    for (int r = 0; r < 4; ++r) {
      int m = m0 + wv * 16 + quad * 4 + r;
      if (m < M) Pz[(size_t)m * N + n] = acc[j][r];
    }
  }
}

// ---------------------------------------------------------------------------
// K5: split-K reduce: C = relu(sum_z P[z] + bias). float4-vectorized.
// ---------------------------------------------------------------------------
template <typename OutT, int KS>
__global__ __launch_bounds__(256) void k_reduce(const float* __restrict__ P,
    const float* __restrict__ bias, OutT* __restrict__ C, int MN, int N) {
  int i = blockIdx.x * 256 + threadIdx.x;   // float4 index
  if (i * 4 >= MN) return;
  f32x4 s = *(const f32x4*)(P + (size_t)i * 4);
#pragma unroll
  for (int z = 1; z < KS; ++z)
    s += *(const f32x4*)(P + (size_t)z * MN + i * 4);
  int n = (i * 4) % N;
#pragma unroll
  for (int u = 0; u < 4; ++u)
    store_o(C, (size_t)i * 4 + u, fmaxf(s[u] + bias[n + u], 0.f));
}

// ---------------------------------------------------------------------------
// K6: heads. One block per row, one wave per output (5 cls + 5 bbox).
// Output fp32, concat [class_logits(800x5); obb_preds(800x5)].
// ---------------------------------------------------------------------------
__global__ __launch_bounds__(640) void k_heads(const float* __restrict__ x2,
    const float* __restrict__ cls_w, const float* __restrict__ cls_b,
    const float* __restrict__ bbox_w, const float* __restrict__ bbox_b,
    float* __restrict__ out) {
  int n = blockIdx.x;
  int wave = threadIdx.x >> 6;   // 0..9
  int lane = threadIdx.x & 63;
  const float* w = (wave < 5) ? (cls_w + (size_t)wave * 1024)
                              : (bbox_w + (size_t)(wave - 5) * 1024);
  const float* xr = x2 + (size_t)n * 1024;
  float s = 0.f;
  for (int k = lane; k < 1024; k += 64) s += xr[k] * w[k];
  for (int off = 32; off; off >>= 1) s += __shfl_down(s, off, 64);
  if (lane == 0) {
    int o = (wave < 5) ? wave : wave - 5;
    float bias = (wave < 5) ? cls_b[o] : bbox_b[o];
    int base = (wave < 5) ? 0 : 4000;
    out[base + n * 5 + o] = s + bias;
  }
}

// ---------------------------------------------------------------------------
extern "C" void kernel_launch(void* const* d_in, const int* in_sizes, int n_in,
                              void* d_out, int out_size, void* d_ws, size_t ws_size,
                              hipStream_t stream) {
  const float* images     = (const float*)d_in[0];
  const float* backbone_w = (const float*)d_in[1];
  const float* backbone_b = (const float*)d_in[2];
  const float* rpn_w      = (const float*)d_in[3];
  const float* rpn_b      = (const float*)d_in[4];
  // d_in[5]/d_in[6] (obj_w/obj_b): conv output unused by the reference.
  const float* delta_w    = (const float*)d_in[7];
  const float* delta_b    = (const float*)d_in[8];
  const float* fc1_w      = (const float*)d_in[9];
  const float* fc1_b      = (const float*)d_in[10];
  const float* fc2_w      = (const float*)d_in[11];
  const float* fc2_b      = (const float*)d_in[12];
  const float* cls_w      = (const float*)d_in[13];
  const float* cls_b      = (const float*)d_in[14];
  const float* bbox_w     = (const float*)d_in[15];
  const float* bbox_b     = (const float*)d_in[16];

  char* ws = (char*)d_ws;
  float* f      = (float*)ws;                  //  8,388,608 B : f NHWC fp32
  float* boxes  = (float*)(ws + 8388608);      //     16,384 B (padded)
  bf16*  pooled = (bf16*) (ws + 8404992);      // 20,070,400 B : 800x12544 bf16
  bf16*  x1     = (bf16*) (ws + 28475392);     //  1,638,400 B : 800x1024 bf16
  float* x2     = (float*)(ws + 30113792);     //  3,276,800 B : 800x1024 fp32
  float* parts  = (float*)(ws + 33390592);     // 19,660,800 B : 6x800x1024 fp32
                                               // total 53.05 MB (<55.1 proven)

  k_backbone<<<8192, 256, 0, stream>>>(images, backbone_w, backbone_b, f);
  k_proposals<<<32, 256, 0, stream>>>(f, rpn_w, rpn_b, delta_w, delta_b, boxes);
  k_roialign<<<800, 256, 0, stream>>>(f, boxes, pooled);

  // FC1: K=12544, split 6 (KC=2112: 5x33+31 iters of 64)
  k_gemm_sk<<<dim3(16, 13, 6), 256, 0, stream>>>(
      (const unsigned short*)pooled, fc1_w, parts, 800, 1024, 12544, 2112);
  k_reduce<bf16, 6><<<800, 256, 0, stream>>>(parts, fc1_b, x1, 819200, 1024);

  // FC2: K=1024, split 4 (KC=256)
  k_gemm_sk<<<dim3(16, 13, 4), 256, 0, stream>>>(
      (const unsigned short*)x1, fc2_w, parts, 800, 1024, 1024, 256);
  k_reduce<float, 4><<<800, 256, 0, stream>>>(parts, fc2_b, x2, 819200, 1024);

  k_heads<<<800, 640, 0, stream>>>(x2, cls_w, cls_b, bbox_w, bbox_b, (float*)d_out);
}